// Round 15
// baseline (195.667 us; speedup 1.0000x reference)
//
#include <hip/hip_runtime.h>
#include <hip/hip_bf16.h>

// VQ-VAE vector quantizer, MI355X. z:(16,512,64,64) f32, codebook:(1024,512) f32.
// d_out f32: z_q (33554432), loss (1), idx (65536).
// R15: 1024 blocks = 512 px-groups x 2 cb halves (3 blocks/CU), cbT coalesced
// staging, zswz prologue, top-4/half with idx-in-mantissa, k1m merge, k2a oct.

typedef _Float16 h8 __attribute__((ext_vector_type(8)));
typedef float f32x16 __attribute__((ext_vector_type(16)));

#define OUT_LOSS  33554432
#define OUT_IDX   33554433
#define MARGIN_T  0.17f      // 0.15 + embed-perturbation slack (2*0.008)
#define FLAG_CAP  32768

struct ull2 { unsigned long long lo, hi; };

__device__ __forceinline__ void gload_lds16(const void* g, void* l) {
  __builtin_amdgcn_global_load_lds(
      (const __attribute__((address_space(1))) void*)g,
      (__attribute__((address_space(3))) void*)l, 16, 0, 0);
}

__device__ __forceinline__ int zswz(int row) {
  return ((row & 3) << 6) | (((row >> 2) & 3) << 4);
}

// embed 10-bit idx into low mantissa bits (perturbs value by <= ~0.008)
__device__ __forceinline__ float embed(float v, int idx) {
  unsigned u = (__float_as_uint(v) & ~1023u) | (unsigned)idx;
  return __uint_as_float(u);
}

// ---- K0: cb fp32 -> fp16 FRAGMENT-STREAM cbT + fold-ordered 0.5||c||^2 -------
__global__ __launch_bounds__(64) void k0_prep(
    const float* __restrict__ cb, unsigned short* __restrict__ cbT,
    float* __restrict__ cnp, int* __restrict__ counters, float* __restrict__ loss_acc)
{
  const int r = blockIdx.x, l = threadIdx.x;
  const float* row = cb + (size_t)r * 512;
  float4 a  = *(const float4*)(row + l * 8);
  float4 b4 = *(const float4*)(row + l * 8 + 4);
  h8 hv;
  hv[0] = (_Float16)a.x;  hv[1] = (_Float16)a.y;  hv[2] = (_Float16)a.z;  hv[3] = (_Float16)a.w;
  hv[4] = (_Float16)b4.x; hv[5] = (_Float16)b4.y; hv[6] = (_Float16)b4.z; hv[7] = (_Float16)b4.w;
  {
    const int c  = r >> 5, rr = r & 31;
    const int s  = l >> 1;                    // k-slot (16 channels)
    const int hk = l & 1;                     // k-half within slot
    char* dst = reinterpret_cast<char*>(cbT)
              + (size_t)(c * 32 + s) * 1024 + (hk * 32 + rr) * 16;
    *reinterpret_cast<h8*>(dst) = hv;
  }
  float s = a.x*a.x + a.y*a.y + a.z*a.z + a.w*a.w
          + b4.x*b4.x + b4.y*b4.y + b4.z*b4.z + b4.w*b4.w;
  #pragma unroll
  for (int off = 1; off < 64; off <<= 1) s += __shfl_xor(s, off);
  if (l == 0) {
    int jr = r & 31, c = r >> 5;
    int khalf = (jr >> 2) & 1;
    int pat = jr - (khalf << 2);
    int rr2 = (pat & 3) + ((pat >> 3) << 2);
    cnp[(c << 5) + (khalf << 4) + rr2] = 0.5f * s;
  }
  if (r == 0 && l < 4) counters[l] = 0;
  if (r == 0 && l == 0) *loss_acc = 0.f;
}

// ---- K1: half-codebook MFMA scan, 1024 blocks (3/CU), top-4 per half ---------
// bid = pxg*2 + hc. 256 thr (4 waves), 128 px. dynLDS = 3*16384 + 2048 = 51200.
__global__ __launch_bounds__(256, 2) void k1_main(
    const float* __restrict__ z, const unsigned short* __restrict__ cbT,
    const float* __restrict__ cnp, float4* __restrict__ partial)
{
  extern __shared__ char smem[];
  float* cn_lds = reinterpret_cast<float*>(smem + 49152);
  const int tid   = threadIdx.x;
  const int lane  = tid & 63;
  const int wave  = tid >> 6;
  const int pxl   = lane & 31;
  const int khalf = lane >> 5;
  const int bid   = blockIdx.x;
  const int pxg   = bid >> 1;
  const int hc    = bid & 1;
  const int px0   = pxg << 7;          // 128 px
  const int b     = px0 >> 12;
  const int hw0   = px0 & 4095;
  const char* cbH = reinterpret_cast<const char*>(cbT) + hc * 524288;

  // ---- z prologue: 4 passes of [128 px][128 ch] fp16 tile (32KB), zswz ------
  h8 bfrag[32];
  for (int i = tid; i < 512; i += 256) cn_lds[i] = cnp[hc * 512 + i];
  #pragma unroll
  for (int p = 0; p < 4; ++p) {
    #pragma unroll
    for (int it2 = 0; it2 < 2; ++it2) {
      const int cg  = tid >> 5;                    // 0..7
      const int ch0 = it2 * 64 + cg * 8;
      const int pq  = (tid & 31) * 4;
      const float* src = z + ((size_t)(b * 512 + p * 128 + ch0)) * 4096 + hw0 + pq;
      float4 v[8];
      #pragma unroll
      for (int j = 0; j < 8; ++j) v[j] = *(const float4*)(src + (size_t)j * 4096);
      const float* vf = reinterpret_cast<const float*>(v);
      #pragma unroll
      for (int dp = 0; dp < 4; ++dp) {
        h8 hv;
        #pragma unroll
        for (int j = 0; j < 8; ++j) hv[j] = (_Float16)vf[j * 4 + dp];
        int row = pq + dp;
        int a = (row << 8) + ch0 * 2;
        a ^= zswz(row);
        *reinterpret_cast<h8*>(smem + a) = hv;
      }
    }
    __syncthreads();
    {
      const int row  = (wave << 5) + pxl;
      const int sw   = zswz(row);
      const int base = (row << 8) + (khalf << 4);
      #pragma unroll
      for (int ss = 0; ss < 8; ++ss)
        bfrag[p * 8 + ss] = *reinterpret_cast<const h8*>(smem + ((base + (ss << 5)) ^ sw));
    }
    __syncthreads();
  }

  // ---- stage chunk 0 (both halves): contiguous 16KB, coalesced --------------
  #pragma unroll
  for (int i = 0; i < 4; ++i)
    gload_lds16(cbH + tid * 16 + i * 4096, smem + tid * 16 + i * 4096);
  #pragma unroll
  for (int i = 0; i < 4; ++i)
    gload_lds16(cbH + 16384 + tid * 16 + i * 4096, smem + 16384 + tid * 16 + i * 4096);
  __syncthreads();   // drains all vmem: vmcnt = 0

  float v0 = INFINITY, v1 = INFINITY, v2 = INFINITY, v3 = INFINITY;
  int   i0 = 0, i1 = 0, i2 = 0, i3 = 0;
  f32x16 acca, accb;
  #pragma unroll
  for (int i = 0; i < 16; ++i) { acca[i] = 0.f; accb[i] = 0.f; }

  char* p0 = smem; char* p1 = smem + 16384; char* p2 = smem + 32768;

  for (int c = 0; c < 16; ++c) {
    const bool pf = (c < 15);
    // half h=0
    asm volatile("s_waitcnt vmcnt(4)" ::: "memory");
    __builtin_amdgcn_s_barrier();
    __builtin_amdgcn_sched_barrier(0);
    if (pf) {
      const char* src = cbH + (c + 1) * 32768 + tid * 16;
      #pragma unroll
      for (int i = 0; i < 4; ++i)
        gload_lds16(src + i * 4096, p2 + tid * 16 + i * 4096);
    }
    {
      const char* ab = p0 + (khalf << 9) + (pxl << 4);
      h8 f[16];
      #pragma unroll
      for (int q = 0; q < 16; ++q) f[q] = *reinterpret_cast<const h8*>(ab + (q << 10));
      __builtin_amdgcn_s_setprio(1);
      #pragma unroll
      for (int q = 0; q < 8; ++q) {
        acca = __builtin_amdgcn_mfma_f32_32x32x16_f16(f[q],     bfrag[q],     acca, 0, 0, 0);
        accb = __builtin_amdgcn_mfma_f32_32x32x16_f16(f[q + 8], bfrag[q + 8], accb, 0, 0, 0);
      }
      __builtin_amdgcn_s_setprio(0);
    }
    { char* t = p0; p0 = p1; p1 = p2; p2 = t; }
    // half h=1
    if (pf) { asm volatile("s_waitcnt vmcnt(4)" ::: "memory"); }
    else    { asm volatile("s_waitcnt vmcnt(0)" ::: "memory"); }
    __builtin_amdgcn_s_barrier();
    __builtin_amdgcn_sched_barrier(0);
    if (pf) {
      const char* src = cbH + (c + 1) * 32768 + 16384 + tid * 16;
      #pragma unroll
      for (int i = 0; i < 4; ++i)
        gload_lds16(src + i * 4096, p2 + tid * 16 + i * 4096);
    }
    {
      const char* ab = p0 + (khalf << 9) + (pxl << 4);
      h8 f[16];
      #pragma unroll
      for (int q = 0; q < 16; ++q) f[q] = *reinterpret_cast<const h8*>(ab + (q << 10));
      __builtin_amdgcn_s_setprio(1);
      #pragma unroll
      for (int q = 0; q < 8; ++q) {
        acca = __builtin_amdgcn_mfma_f32_32x32x16_f16(f[q],     bfrag[16 + q], acca, 0, 0, 0);
        accb = __builtin_amdgcn_mfma_f32_32x32x16_f16(f[q + 8], bfrag[24 + q], accb, 0, 0, 0);
      }
      __builtin_amdgcn_s_setprio(0);
    }
    { char* t = p0; p0 = p1; p1 = p2; p2 = t; }

    // fold chunk: top-4 (global code id via hc offset)
    {
      const float* cl = cn_lds + (c << 5) + (khalf << 4);
      float4 q0 = *(const float4*)(cl);     float4 q1 = *(const float4*)(cl + 4);
      float4 q2 = *(const float4*)(cl + 8); float4 q3 = *(const float4*)(cl + 12);
      const float cn[16] = {q0.x,q0.y,q0.z,q0.w, q1.x,q1.y,q1.z,q1.w,
                            q2.x,q2.y,q2.z,q2.w, q3.x,q3.y,q3.z,q3.w};
      float sc[16];
      #pragma unroll
      for (int r = 0; r < 16; ++r) sc[r] = cn[r] - (acca[r] + accb[r]);
      float mn = sc[0];
      #pragma unroll
      for (int r = 1; r < 16; ++r) mn = fminf(mn, sc[r]);
      if (__ballot(mn < v3)) {
        const int jbase = hc * 512 + (c << 5) + (khalf << 2);
        #pragma unroll
        for (int r = 0; r < 16; ++r) {
          int j = jbase + ((r & 3) + ((r >> 2) << 3));
          float s = sc[r];
          bool c0 = s < v0, c1 = s < v1, c2 = s < v2, c3 = s < v3;
          v3 = c2 ? v2 : (c3 ? s : v3);  i3 = c2 ? i2 : (c3 ? j : i3);
          v2 = c1 ? v1 : (c2 ? s : v2);  i2 = c1 ? i1 : (c2 ? j : i2);
          v1 = c0 ? v0 : (c1 ? s : v1);  i1 = c0 ? i0 : (c1 ? j : i1);
          v0 = c0 ? s  : v0;             i0 = c0 ? j  : i0;
        }
      }
      #pragma unroll
      for (int i = 0; i < 16; ++i) { acca[i] = 0.f; accb[i] = 0.f; }
    }
  }

  // merge khalf halves: snapshot partner's list BEFORE mutating ours
  {
    float ow0 = __shfl_xor(v0, 32), ow1 = __shfl_xor(v1, 32),
          ow2 = __shfl_xor(v2, 32), ow3 = __shfl_xor(v3, 32);
    int   oj0 = __shfl_xor(i0, 32), oj1 = __shfl_xor(i1, 32),
          oj2 = __shfl_xor(i2, 32), oj3 = __shfl_xor(i3, 32);
    const float ow[4] = {ow0, ow1, ow2, ow3};
    const int   oj[4] = {oj0, oj1, oj2, oj3};
    #pragma unroll
    for (int k = 0; k < 4; ++k) {
      float ov = ow[k]; int oi = oj[k];
      bool c0 = ov < v0, c1 = ov < v1, c2 = ov < v2, c3 = ov < v3;
      v3 = c2 ? v2 : (c3 ? ov : v3);  i3 = c2 ? i2 : (c3 ? oi : i3);
      v2 = c1 ? v1 : (c2 ? ov : v2);  i2 = c1 ? i1 : (c2 ? oi : i2);
      v1 = c0 ? v0 : (c1 ? ov : v1);  i1 = c0 ? i0 : (c1 ? oi : i1);
      v0 = c0 ? ov : v0;              i0 = c0 ? oi : i0;
    }
  }

  if (lane < 32) {
    const int pix = px0 + (wave << 5) + lane;
    float4 e;
    e.x = embed(v0, i0); e.y = embed(v1, i1);
    e.z = embed(v2, i2); e.w = embed(v3, i3);
    partial[hc * 65536 + pix] = e;
  }
}

// ---- K1m: merge the 2 halves' top-4, classify, emit ---------------------------
__global__ __launch_bounds__(256) void k1_merge(
    const float4* __restrict__ partial,
    int* __restrict__ idx_ws, unsigned long long* __restrict__ packed_ws,
    int* __restrict__ flaglist, ull2* __restrict__ pairlist, int* __restrict__ counters)
{
  const int pix  = blockIdx.x * 256 + threadIdx.x;
  const int lane = threadIdx.x & 63;
  float4 A = partial[pix], B = partial[65536 + pix];
  const float cv[8] = {A.x, A.y, A.z, A.w, B.x, B.y, B.z, B.w};
  int id[8];
  #pragma unroll
  for (int j = 0; j < 8; ++j) id[j] = (int)(__float_as_uint(cv[j]) & 1023u);

  // merged top-4 of the 8 (values carry embedded idx; margins widened for it)
  float w0 = INFINITY, w1 = INFINITY, w2 = INFINITY, w3 = INFINITY;
  int   j0 = 0;
  #pragma unroll
  for (int k = 0; k < 8; ++k) {
    float v = cv[k];
    bool c0 = v < w0, c1 = v < w1, c2 = v < w2, c3 = v < w3;
    w3 = c2 ? w2 : (c3 ? v : w3);
    w2 = c1 ? w1 : (c2 ? v : w2);
    w1 = c0 ? w0 : (c1 ? v : w1);
    if (c0) { w0 = v; j0 = id[k]; }
  }
  float cert = fminf(A.w, B.w);        // codes outside the 8 are >= their half's v3
  bool sane = (w0 == w0) && (w1 == w1) && (cert == cert);
  bool unfl = sane && (w1 - w0 >= MARGIN_T);
  bool oct  = sane && !unfl && (cert - w0 >= MARGIN_T);
  bool full = !unfl && !oct;
  idx_ws[pix] = unfl ? j0 : (int)0x80000000;
  if (!unfl) packed_ws[pix] = ~0ull;

  unsigned long long qm = __ballot(oct);
  if (qm) {
    int leader = __ffsll(qm) - 1;
    int base = 0;
    if (lane == leader) base = atomicAdd(&counters[1], __popcll(qm));
    base = __shfl(base, leader);
    if (oct) {
      int pos = __popcll(qm & ((1ull << lane) - 1ull));
      ull2 e;
      e.lo = (unsigned long long)(unsigned)pix
           | ((unsigned long long)(unsigned)id[0] << 16)
           | ((unsigned long long)(unsigned)id[1] << 26)
           | ((unsigned long long)(unsigned)id[2] << 36)
           | ((unsigned long long)(unsigned)id[3] << 46);
      e.hi = (unsigned long long)(unsigned)id[4]
           | ((unsigned long long)(unsigned)id[5] << 10)
           | ((unsigned long long)(unsigned)id[6] << 20)
           | ((unsigned long long)(unsigned)id[7] << 30);
      pairlist[base + pos] = e;
    }
  }
  unsigned long long fm = __ballot(full);
  if (fm) {
    int leader = __ffsll(fm) - 1;
    int base = 0;
    if (lane == leader) base = atomicAdd(&counters[0], __popcll(fm));
    base = __shfl(base, leader);
    if (full) {
      int pos = __popcll(fm & ((1ull << lane) - 1ull));
      int wi = base + pos;
      if (wi < FLAG_CAP) flaglist[wi] = pix;
    }
  }
}

// ---- K2a: exact fp64 check of 8 candidates, one wave per pixel ----------------
__global__ __launch_bounds__(256) void k2a_oct(
    const float* __restrict__ z, const float* __restrict__ cb,
    const ull2* __restrict__ pairlist, const int* __restrict__ counters,
    int* __restrict__ idx_ws)
{
  const int lane = threadIdx.x & 63;
  const int wid  = (blockIdx.x << 2) + (threadIdx.x >> 6);
  const int nwav = gridDim.x << 2;
  const int nf   = counters[1];
  for (int e = wid; e < nf; e += nwav) {
    ull2 pk = pairlist[e];
    int pix = (int)(pk.lo & 0xFFFFull);
    int cd[8];
    cd[0] = (int)((pk.lo >> 16) & 1023ull); cd[1] = (int)((pk.lo >> 26) & 1023ull);
    cd[2] = (int)((pk.lo >> 36) & 1023ull); cd[3] = (int)((pk.lo >> 46) & 1023ull);
    cd[4] = (int)(pk.hi & 1023ull);         cd[5] = (int)((pk.hi >> 10) & 1023ull);
    cd[6] = (int)((pk.hi >> 20) & 1023ull); cd[7] = (int)((pk.hi >> 30) & 1023ull);
    const float* zp = z + (size_t)(pix >> 12) * 512 * 4096 + (pix & 4095);
    double s[8];
    #pragma unroll
    for (int j = 0; j < 8; ++j) s[j] = 0.0;
    #pragma unroll
    for (int k = 0; k < 8; ++k) {
      int c = lane + (k << 6);
      double zv2 = 2.0 * (double)zp[(size_t)c * 4096];
      #pragma unroll
      for (int j = 0; j < 8; ++j) {
        double a = (double)cb[(size_t)cd[j] * 512 + c];
        s[j] = fma(a, a - zv2, s[j]);
      }
    }
    #pragma unroll
    for (int j = 0; j < 8; ++j) {
      #pragma unroll
      for (int off = 32; off > 0; off >>= 1) s[j] += __shfl_xor(s[j], off);
    }
    double bv = s[0]; int bi = cd[0];
    #pragma unroll
    for (int j = 1; j < 8; ++j) {
      if (s[j] < bv || (s[j] == bv && cd[j] < bi)) { bv = s[j]; bi = cd[j]; }
    }
    if (lane == 0) idx_ws[pix] = bi;
  }
}

// ---- K2b: exact fp64 full re-rank (rare) ---------------------------------------
__global__ __launch_bounds__(256) void k2_rescan(
    const float* __restrict__ z, const float* __restrict__ cb,
    const int* __restrict__ flaglist, const int* __restrict__ counters,
    unsigned long long* __restrict__ packed_ws)
{
  __shared__ float zb[16][512];
  __shared__ unsigned long long best[16];
  __shared__ int pixl[16];
  const int t = threadIdx.x;
  int nflag = counters[0];
  if (nflag > FLAG_CAP) nflag = FLAG_CAP;
  const int ntasks = ((nflag + 15) >> 4) << 2;
  for (int task = blockIdx.x; task < ntasks; task += gridDim.x) {
    const int g = task >> 2, q = task & 3;
    int rem = nflag - (g << 4);
    const int npx = rem < 16 ? rem : 16;
    if (t < 16) {
      best[t] = ~0ull;
      pixl[t] = (t < npx) ? flaglist[(g << 4) + t] : 0;
    }
    __syncthreads();
    for (int i = t; i < (npx << 9); i += 256) {
      int p = i >> 9, c = i & 511;
      int pix = pixl[p];
      zb[p][c] = z[((size_t)(pix >> 12) * 512 + c) * 4096 + (pix & 4095)];
    }
    __syncthreads();
    const int j = (q << 8) + t;
    const float* row = cb + (size_t)j * 512;
    double dot[16];
    #pragma unroll
    for (int p = 0; p < 16; ++p) dot[p] = 0.0;
    double cn = 0.0;
    for (int k = 0; k < 512; k += 4) {
      float4 cv = *(const float4*)(row + k);
      double c0 = cv.x, c1 = cv.y, c2 = cv.z, c3 = cv.w;
      cn = fma(c0, c0, cn); cn = fma(c1, c1, cn);
      cn = fma(c2, c2, cn); cn = fma(c3, c3, cn);
      #pragma unroll
      for (int p = 0; p < 16; ++p) {
        dot[p] = fma(c0, (double)zb[p][k + 0], dot[p]);
        dot[p] = fma(c1, (double)zb[p][k + 1], dot[p]);
        dot[p] = fma(c2, (double)zb[p][k + 2], dot[p]);
        dot[p] = fma(c3, (double)zb[p][k + 3], dot[p]);
      }
    }
    #pragma unroll
    for (int p = 0; p < 16; ++p) {
      if (p < npx) {
        double d = fma(-2.0, dot[p], cn);
        unsigned long long u = (unsigned long long)__double_as_longlong(d);
        u = (u >> 63) ? ~u : (u | 0x8000000000000000ull);
        unsigned long long pkk = (u & ~1023ull) | (unsigned long long)j;
        atomicMin(&best[p], pkk);
      }
    }
    __syncthreads();
    if (t < npx) atomicMin(&packed_ws[pixl[t]], best[t]);
    __syncthreads();
  }
}

// ---- K3: gather + transpose-write z_q (f32), idx (f32), loss ------------------
__global__ __launch_bounds__(256) void k3_out(
    const float* __restrict__ z, const float* __restrict__ cb,
    const int* __restrict__ idx_ws, const unsigned long long* __restrict__ packed_ws,
    float* __restrict__ out, float* __restrict__ loss_acc)
{
  extern __shared__ float rows[];
  __shared__ int idxs[32];
  __shared__ float wsum[4];
  const int t = threadIdx.x;
  const int pix0 = blockIdx.x << 5;
  const int b = pix0 >> 12, hw0 = pix0 & 4095;
  if (t < 32) {
    int pix = pix0 + t;
    int v = idx_ws[pix];
    unsigned j = (v < 0) ? (unsigned)(packed_ws[pix] & 1023ull) : (unsigned)v;
    j &= 1023u;
    idxs[t] = (int)j;
    out[OUT_IDX + pix] = (float)j;
  }
  __syncthreads();
  for (int i = t; i < 32 * 128; i += 256) {
    int r = i >> 7, kq = (i & 127) << 2;
    float4 v = *(const float4*)(cb + (size_t)idxs[r] * 512 + kq);
    float* dst = rows + r * 513 + kq;
    dst[0] = v.x; dst[1] = v.y; dst[2] = v.z; dst[3] = v.w;
  }
  __syncthreads();
  const int pl = (t & 7) << 2;
  const int cg = t >> 3;
  float acc = 0.f;
  for (int c0 = 0; c0 < 512; c0 += 32) {
    int c = c0 + cg;
    size_t go = ((size_t)(b * 512 + c)) * 4096 + hw0 + pl;
    float4 zv = *(const float4*)(z + go);
    float q0 = rows[(pl + 0) * 513 + c], q1 = rows[(pl + 1) * 513 + c];
    float q2 = rows[(pl + 2) * 513 + c], q3 = rows[(pl + 3) * 513 + c];
    float d0 = q0 - zv.x, d1 = q1 - zv.y, d2 = q2 - zv.z, d3 = q3 - zv.w;
    acc = fmaf(d0, d0, acc); acc = fmaf(d1, d1, acc);
    acc = fmaf(d2, d2, acc); acc = fmaf(d3, d3, acc);
    float4 qv;
    qv.x = zv.x + d0; qv.y = zv.y + d1;
    qv.z = zv.z + d2; qv.w = zv.w + d3;
    *reinterpret_cast<float4*>(out + go) = qv;
  }
  #pragma unroll
  for (int off = 32; off > 0; off >>= 1) acc += __shfl_down(acc, off);
  if ((t & 63) == 0) wsum[t >> 6] = acc;
  __syncthreads();
  if (t == 0) atomicAdd(loss_acc, wsum[0] + wsum[1] + wsum[2] + wsum[3]);
}

__global__ void k4_loss(const float* __restrict__ loss_acc, float* __restrict__ out)
{
  if (threadIdx.x == 0 && blockIdx.x == 0)
    out[OUT_LOSS] = loss_acc[0] * (1.25f / 33554432.f);
}

// ---- launch --------------------------------------------------------------------
extern "C" void kernel_launch(void* const* d_in, const int* in_sizes, int n_in,
                              void* d_out, int out_size, void* d_ws, size_t ws_size,
                              hipStream_t stream) {
  const float* z  = (const float*)d_in[0];
  const float* cb = (const float*)d_in[1];
  float* out = (float*)d_out;
  char* ws = (char*)d_ws;
  // [0,1M): cbT (dead after k1) — pairlist overlays [0,256K) at k1m time.
  unsigned short*      cbT       = (unsigned short*)(ws);
  ull2*                pairlist  = (ull2*)(ws);
  float4*              partial   = (float4*)(ws + 1048576);    // 2 MB
  int*                 idx_ws    = (int*)(ws + 3145728);       // 256 KB
  unsigned long long*  packed_ws = (unsigned long long*)(ws + 3407872); // 512 KB
  int*                 flaglist  = (int*)(ws + 3932160);       // 128 KB
  float*               cnp       = (float*)(ws + 4063232);     // 4 KB
  int*                 counters  = (int*)(ws + 4067328);
  float*               loss_acc  = (float*)(ws + 4067392);

  (void)hipFuncSetAttribute((const void*)k1_main,
        hipFuncAttributeMaxDynamicSharedMemorySize, 51200);
  (void)hipFuncSetAttribute((const void*)k3_out,
        hipFuncAttributeMaxDynamicSharedMemorySize, 65664);

  k0_prep<<<1024, 64, 0, stream>>>(cb, cbT, cnp, counters, loss_acc);
  k1_main<<<1024, 256, 51200, stream>>>(z, cbT, cnp, partial);
  k1_merge<<<256, 256, 0, stream>>>(partial, idx_ws, packed_ws, flaglist, pairlist, counters);
  k2a_oct<<<512, 256, 0, stream>>>(z, cb, pairlist, counters, idx_ws);
  k2_rescan<<<256, 256, 0, stream>>>(z, cb, flaglist, counters, packed_ws);
  k3_out<<<2048, 256, 65664, stream>>>(z, cb, idx_ws, packed_ws, out, loss_acc);
  k4_loss<<<1, 1, 0, stream>>>(loss_acc, out);
}